// Round 10
// baseline (1579.742 us; speedup 1.0000x reference)
//
#include <hip/hip_runtime.h>
#include <hip/hip_fp16.h>

#define BS 256
#define T 256
#define STEPS 255
#define WV 100
#define INP 64
#define H 256
#define G4 1024
#define VOCAB 600
#define VT 38            // vocab tiles of 16 (608, padded)

// ---------------- packed f16 dot2 with f32 accumulate ---------------------
typedef _Float16 f16x2 __attribute__((ext_vector_type(2)));
typedef _Float16 f16x8 __attribute__((ext_vector_type(8)));
typedef float f32x4 __attribute__((ext_vector_type(4)));

__device__ __forceinline__ float fdot2(unsigned w, unsigned h, float acc) {
#if defined(__has_builtin) && __has_builtin(__builtin_amdgcn_fdot2)
    return __builtin_amdgcn_fdot2(__builtin_bit_cast(f16x2, w),
                                  __builtin_bit_cast(f16x2, h), acc, false);
#else
    __half2 wv = *(const __half2*)&w;
    __half2 hv = *(const __half2*)&h;
    float2 wf = __half22float2(wv), hf = __half22float2(hv);
    return acc + wf.x * hf.x + wf.y * hf.y;
#endif
}

// quad (4-lane) sum via DPP quad_perm xor1 + xor2 — VALU pipe, no LDS.
// Butterfly: every lane ends with the bitwise-identical total.
__device__ __forceinline__ float quad_reduce(float x) {
    int a = __builtin_bit_cast(int, x);
    int b = __builtin_amdgcn_update_dpp(0, a, 0xB1, 0xF, 0xF, true);  // [1,0,3,2]
    float s = x + __builtin_bit_cast(float, b);
    int c = __builtin_bit_cast(int, s);
    int d = __builtin_amdgcn_update_dpp(0, c, 0x4E, 0xF, 0xF, true);  // [2,3,0,1]
    return s + __builtin_bit_cast(float, d);
}

__device__ __forceinline__ f32x4 mfma16(uint4 a, uint4 b, f32x4 c) {
    return __builtin_amdgcn_mfma_f32_16x16x32_f16(
        __builtin_bit_cast(f16x8, a), __builtin_bit_cast(f16x8, b), c, 0, 0, 0);
}

// ---------------- sort: stable descending by length (jax argsort(-len)) ----
__global__ void k_sort(const int* __restrict__ lens, int* __restrict__ sidx,
                       int* __restrict__ dlen, float* __restrict__ out_dec,
                       float* __restrict__ out_sidx) {
    __shared__ int L[BS];
    int i = threadIdx.x;
    L[i] = lens[i];
    __syncthreads();
    int li = L[i];
    int r = 0;
    for (int j = 0; j < BS; ++j) {
        int lj = L[j];
        r += (lj > li) || (lj == li && j < i);
    }
    sidx[r] = i;
    dlen[r] = li - 1;
    out_sidx[r] = (float)i;
    out_dec[r]  = (float)(li - 1);
}

// ---------------- gather sorted captions to output ------------------------
__global__ void k_gather(const float* __restrict__ cin, const int* __restrict__ sidx,
                         float* __restrict__ cout) {
    int b = blockIdx.x;
    int src = sidx[b];
    const float4* in  = (const float4*)(cin + (size_t)src * T * WV);
    float4* out       = (float4*)(cout + (size_t)b * T * WV);
    for (int i = threadIdx.x; i < T * WV / 4; i += 256) out[i] = in[i];
}

// ---------------- W_comb = w_ih @ W_emb^T  [1024 x 100] -------------------
__global__ void k_wcomb(const float* __restrict__ w_ih, const float* __restrict__ W_emb,
                        float* __restrict__ Wc) {
    int idx = blockIdx.x * 256 + threadIdx.x;   // 102400 threads
    int r = idx / WV, cc = idx % WV;
    float acc = 0.f;
    for (int k = 0; k < INP; ++k) acc += w_ih[r * INP + k] * W_emb[k * WV + cc];
    Wc[idx] = acc;
}

// ---------------- b_comb = b_ih + b_hh + w_ih @ b_emb ---------------------
__global__ void k_bcomb(const float* __restrict__ w_ih, const float* __restrict__ b_ih,
                        const float* __restrict__ b_hh, const float* __restrict__ b_emb,
                        float* __restrict__ bc) {
    int r = blockIdx.x * 256 + threadIdx.x;     // 1024 threads
    float acc = b_ih[r] + b_hh[r];
    for (int k = 0; k < INP; ++k) acc += w_ih[r * INP + k] * b_emb[k];
    bc[r] = acc;
}

// ---------------- pack w_hh -> fp16, ROW-major half2 ----------------------
__global__ void k_packw(const float* __restrict__ w_hh, __half2* __restrict__ wR) {
    int idx = blockIdx.x * 256 + threadIdx.x;   // 131072 threads
    wR[idx] = __floats2half2_rn(w_hh[(size_t)idx * 2], w_hh[(size_t)idx * 2 + 1]);
}

// ---------------- pack o-gate rows into streaming order -------------------
// woq[((u*2+s)*128 + Q)*4 + q] = wR4[(768 + 2Q + s)*32 + q*8 + u]
// Consecutive tid (q fastest, then Q) -> consecutive 16B -> coalesced 1KB
// per wave-inst in k_lstm; region is 128 KB, L2-hot across all 256 blocks.
__global__ void k_packo(const __half2* __restrict__ wR, uint4* __restrict__ woq) {
    int idx = blockIdx.x * 256 + threadIdx.x;   // 8192 threads
    int q = idx & 3, Q = (idx >> 2) & 127, s = (idx >> 9) & 1, u = idx >> 10;
    woq[idx] = ((const uint4*)wR)[(768 + 2 * Q + s) * 32 + q * 8 + u];
}

// ---------------- pack W_out -> hi/lo f16 MFMA-B fragments ----------------
__global__ void k_packwo(const float* __restrict__ Wo, __half* __restrict__ woHi,
                         __half* __restrict__ woLo) {
    int idx = blockIdx.x * 256 + threadIdx.x;   // VT*8*64*8 = 155648 threads
    int fi = idx >> 9;           // vt*8 + kt
    int l  = (idx >> 3) & 63;
    int j  = idx & 7;
    int vt = fi >> 3, kt = fi & 7;
    int v = vt * 16 + (l & 15);
    int k = kt * 32 + ((l >> 4) << 3) + j;
    float w = (v < VOCAB) ? Wo[(size_t)v * H + k] : 0.f;
    __half hi = __float2half(w);
    __half lo = __float2half(w - __half2float(hi));
    woHi[idx] = hi;
    woLo[idx] = lo;
}

// ---------------- pack sorted caps -> hi/lo f16 planes [b][t][128] --------
__global__ void k_packcaps(const float* __restrict__ caps, __half* __restrict__ cHi,
                           __half* __restrict__ cLo) {
    int idx = blockIdx.x * 256 + threadIdx.x;    // BS*T*128 = 8.4M threads
    int k = idx & 127;
    int bt = idx >> 7;
    float v = (k < WV) ? caps[(size_t)bt * WV + k] : 0.f;
    __half hi = __float2half(v);
    cHi[idx] = hi;
    cLo[idx] = __float2half(v - __half2float(hi));
}

// ---------------- pack W_comb -> hi/lo f16 MFMA-B fragments ---------------
__global__ void k_packwc(const float* __restrict__ Wc, __half* __restrict__ wcHi,
                         __half* __restrict__ wcLo) {
    int idx = blockIdx.x * 256 + threadIdx.x;   // 64*4*64*8 = 131072 threads
    int fi = idx >> 9;          // nt*4 + kt
    int l  = (idx >> 3) & 63;
    int j  = idx & 7;
    int nt = fi >> 2, kt = fi & 3;
    int n = nt * 16 + (l & 15);
    int k = kt * 32 + ((l >> 4) << 3) + j;
    float w = (k < WV) ? Wc[(size_t)n * WV + k] : 0.f;
    __half hi = __float2half(w);
    wcHi[idx] = hi;
    wcLo[idx] = __float2half(w - __half2float(hi));
}

// ---------------- h0 = enc@W_h^T + b_h ; c0 = enc@W_c^T + b_c -------------
__global__ void k_inithc(const float* __restrict__ enc, const int* __restrict__ sidx,
                         const float* __restrict__ W_h, const float* __restrict__ b_h,
                         const float* __restrict__ W_c, const float* __restrict__ b_c,
                         float* __restrict__ h_st, float* __restrict__ c_st) {
    int b = blockIdx.x, j = threadIdx.x;
    __shared__ __align__(16) float e[INP];
    int src = sidx[b];
    if (j < INP) e[j] = enc[src * INP + j];
    __syncthreads();
    const float4* e4  = (const float4*)e;
    const float4* wh4 = (const float4*)(W_h + (size_t)j * INP);
    const float4* wc4 = (const float4*)(W_c + (size_t)j * INP);
    float ah = b_h[j], ac = b_c[j];
    #pragma unroll
    for (int k4 = 0; k4 < INP / 4; ++k4) {
        float4 ev = e4[k4];
        float4 wh = wh4[k4];
        float4 wc = wc4[k4];
        ah += ev.x * wh.x + ev.y * wh.y + ev.z * wh.z + ev.w * wh.w;
        ac += ev.x * wc.x + ev.y * wc.y + ev.z * wc.z + ev.w * wc.w;
    }
    h_st[b * H + j] = ah;
    c_st[b * H + j] = ac;
}

// ---------------- xg via MFMA (unchanged from round 8) --------------------
__global__ __launch_bounds__(256) void k_xg(const __half* __restrict__ cHi,
        const __half* __restrict__ cLo, const __half* __restrict__ wcHi,
        const __half* __restrict__ wcLo, const float* __restrict__ bc,
        const int* __restrict__ dlen, float* __restrict__ xg, int t0, int Cc) {
    int b = blockIdx.y;
    int ct0 = blockIdx.x * 32;
    if (t0 + ct0 >= dlen[b]) return;   // rows never consumed by the LSTM
    int tid = threadIdx.x;
    int l = tid & 63, wid = tid >> 6;
    int lhi = l >> 4, llo = l & 15;

    uint4 aH[2][4], aL[2][4];
    #pragma unroll
    for (int m = 0; m < 2; ++m) {
        int rr = ct0 + m * 16 + llo;
        if (rr >= Cc) rr = Cc - 1;              // clamp (store-masked)
        size_t base = ((size_t)b * T + (t0 + rr)) * 128 + lhi * 8;
        #pragma unroll
        for (int kt = 0; kt < 4; ++kt) {
            aH[m][kt] = *(const uint4*)(cHi + base + kt * 32);
            aL[m][kt] = *(const uint4*)(cLo + base + kt * 32);
        }
    }
    const uint4* bh4 = (const uint4*)wcHi;
    const uint4* bl4 = (const uint4*)wcLo;
    for (int i = 0; i < 16; ++i) {
        int nt = wid * 16 + i;
        float bias = bc[nt * 16 + llo];
        f32x4 acc0 = {bias, bias, bias, bias};
        f32x4 acc1 = acc0;
        #pragma unroll
        for (int kt = 0; kt < 4; ++kt) {
            uint4 bh = bh4[(nt * 4 + kt) * 64 + l];
            uint4 bl = bl4[(nt * 4 + kt) * 64 + l];
            acc0 = mfma16(aH[0][kt], bh, acc0);
            acc1 = mfma16(aH[1][kt], bh, acc1);
            acc0 = mfma16(aH[0][kt], bl, acc0);
            acc1 = mfma16(aH[1][kt], bl, acc1);
            acc0 = mfma16(aL[0][kt], bh, acc0);
            acc1 = mfma16(aL[1][kt], bh, acc1);
        }
        #pragma unroll
        for (int m = 0; m < 2; ++m) {
            f32x4 A = m ? acc1 : acc0;
            #pragma unroll
            for (int ii = 0; ii < 4; ++ii) {
                int rr = ct0 + m * 16 + lhi * 4 + ii;
                if (rr < Cc)
                    xg[((size_t)b * Cc + rr) * G4 + nt * 16 + llo] = A[ii];
            }
        }
    }
}

// ---------------- recurrent LSTM core: one block per batch row ------------
// ROUND 10 (on top of round-9 quad-local structure, bitwise-same math):
//  (a) o-gate weights stream from GLOBAL (woq, L2-hot, coalesced) instead of
//      LDS -> LDS pipe only carries the h broadcast (16 b128/thread/step).
//  (b) in-loop barrier is lgkmcnt-only (inline asm): __syncthreads()'s
//      vmcnt(0) drain forced the global hck store + xg/weight loads to
//      COMPLETE every step (~300-900 cy of pure wait).  No in-kernel
//      consumer of those global ops -> drain is unnecessary.
#define LSTM_SMEM (2 * 1152)   // h dbuf: 2 x (hi 144 + lo 144 dwords)

__global__ __launch_bounds__(512)
__attribute__((amdgpu_waves_per_eu(2, 2)))
void k_lstm(const __half2* __restrict__ wR, const uint4* __restrict__ woq,
        const float* __restrict__ xg, const int* __restrict__ dlen,
        float* __restrict__ h_st, float* __restrict__ c_st,
        __half* __restrict__ hck, int t0, int Cc) {
    extern __shared__ __align__(16) char smem[];
    unsigned* hbuf = (unsigned*)smem;            // 2 bufs x (hi 144 + lo 144) dw

    int b = blockIdx.x, tid = threadIdx.x;
    int steps_b = dlen[b];
    if (t0 >= steps_b) return;

    int lane = tid & 63;
    int q = lane & 3;                 // my k-quarter
    int Q = tid >> 2;                 // quad id 0..127, h-rows 2Q, 2Q+1
    int rx = 2 * Q + (q & 1);         // the h-row this lane redundantly owns

    const uint4* wR4 = (const uint4*)wR;

    // gate-row table for this quad: {i r0, i r1, f r0, f r1, g r0, g r1}
    // in regs; {o r0, o r1} streamed from woq (global) each step.
    uint4 wreg[6][8];
    #pragma unroll
    for (int j = 0; j < 6; ++j) {
        int grow = (j >> 1) * 256 + 2 * Q + (j & 1);   // gates i,f,g
        #pragma unroll
        for (int u = 0; u < 8; ++u)
            wreg[j][u] = wR4[grow * 32 + q * 8 + u];
    }

    // init: every lane loads its row's h/c (dup addresses coalesce); q<2 store
    float c = c_st[b * H + rx];
    float hcur = h_st[b * H + rx];
    {
        __half hh16 = __float2half(hcur);
        __half hl16 = __float2half(hcur - __half2float(hh16));
        if (q < 2) {
            int hidx = (rx >> 6) * 72 + (rx & 63);
            ((__half*)(hbuf))[hidx] = hh16;           // buf 0 hi
            ((__half*)(hbuf + 144))[hidx] = hl16;     // buf 0 lo
        }
    }
    __syncthreads();

    int tend = t0 + Cc; if (tend > steps_b) tend = steps_b;
    const float* xgp = xg + (size_t)b * Cc * G4;
    __half* hckp = hck + (size_t)b * Cc * H;
    const uint4* wq = woq + Q * 4 + q;   // stride 512 uint4 per (u,s) slot
    int p = 0;

    for (int t = t0; t < tend; ++t) {
        // xg for my row's 4 gates (issued early, consumed post-reduce)
        float xi = xgp[rx];
        float xf = xgp[256 + rx];
        float xgg = xgp[512 + rx];
        float xo = xgp[768 + rx];

        const uint4* hh4 = (const uint4*)(hbuf + p * 288);
        const uint4* hl4 = (const uint4*)(hbuf + p * 288 + 144);

        float ah[8], al[8];
        #pragma unroll
        for (int j = 0; j < 8; ++j) { ah[j] = 0.f; al[j] = 0.f; }

        #pragma unroll
        for (int u = 0; u < 8; ++u) {
            uint4 hh = hh4[q * 9 + u];
            uint4 hl = hl4[q * 9 + u];
            #pragma unroll
            for (int j = 0; j < 6; ++j) {
                uint4 w = wreg[j][u];
                ah[j] = fdot2(w.x, hh.x, ah[j]);
                ah[j] = fdot2(w.y, hh.y, ah[j]);
                ah[j] = fdot2(w.z, hh.z, ah[j]);
                ah[j] = fdot2(w.w, hh.w, ah[j]);
                al[j] = fdot2(w.x, hl.x, al[j]);
                al[j] = fdot2(w.y, hl.y, al[j]);
                al[j] = fdot2(w.z, hl.z, al[j]);
                al[j] = fdot2(w.w, hl.w, al[j]);
            }
            uint4 w6 = wq[(u * 2 + 0) * 512];
            uint4 w7 = wq[(u * 2 + 1) * 512];
            ah[6] = fdot2(w6.x, hh.x, ah[6]);
            ah[6] = fdot2(w6.y, hh.y, ah[6]);
            ah[6] = fdot2(w6.z, hh.z, ah[6]);
            ah[6] = fdot2(w6.w, hh.w, ah[6]);
            al[6] = fdot2(w6.x, hl.x, al[6]);
            al[6] = fdot2(w6.y, hl.y, al[6]);
            al[6] = fdot2(w6.z, hl.z, al[6]);
            al[6] = fdot2(w6.w, hl.w, al[6]);
            ah[7] = fdot2(w7.x, hh.x, ah[7]);
            ah[7] = fdot2(w7.y, hh.y, ah[7]);
            ah[7] = fdot2(w7.z, hh.z, ah[7]);
            ah[7] = fdot2(w7.w, hh.w, ah[7]);
            al[7] = fdot2(w7.x, hl.x, al[7]);
            al[7] = fdot2(w7.y, hl.y, al[7]);
            al[7] = fdot2(w7.z, hl.z, al[7]);
            al[7] = fdot2(w7.w, hl.w, al[7]);
        }

        // ---- quad reduction (DPP): every lane gets all 8 totals ----
        float tt[8];
        #pragma unroll
        for (int j = 0; j < 8; ++j) tt[j] = quad_reduce(ah[j] + al[j]);

        // static selects on (q&1) — no runtime array indexing (rule #20)
        int odd = q & 1;
        float pi = odd ? tt[1] : tt[0];
        float pf = odd ? tt[3] : tt[2];
        float pg = odd ? tt[5] : tt[4];
        float po = odd ? tt[7] : tt[6];
        float iv = 1.f / (1.f + __expf(-(pi + xi)));
        float fv = 1.f / (1.f + __expf(-(pf + xf)));
        float gv = tanhf(pg + xgg);
        float ov = 1.f / (1.f + __expf(-(po + xo)));
        c = fv * c + iv * gv;
        float nh = ov * tanhf(c);
        hcur = nh;
        __half hh16 = __float2half(nh);
        __half hl16 = __float2half(nh - __half2float(hh16));
        if (q < 2) {
            hckp[rx] = hh16;
            int hidx = (rx >> 6) * 72 + (rx & 63);
            ((__half*)(hbuf + (p ^ 1) * 288))[hidx] = hh16;
            ((__half*)(hbuf + (p ^ 1) * 288 + 144))[hidx] = hl16;
        }
        // lgkmcnt-only barrier: LDS h-writes visible; global ops stay in
        // flight across steps (no in-kernel consumer -> vmcnt drain useless)
        asm volatile("s_waitcnt lgkmcnt(0)\n\ts_barrier" ::: "memory");
        __builtin_amdgcn_sched_barrier(0);
        p ^= 1;
        xgp += G4;
        hckp += H;
    }
    if (q < 2) { h_st[b * H + rx] = hcur; c_st[b * H + rx] = c; }
}

// ---------------- logits via MFMA (unchanged from round 7) ----------------
__global__ __launch_bounds__(64) void k_logits(const __half* __restrict__ hck,
        const __half* __restrict__ woHi, const __half* __restrict__ woLo,
        const float* __restrict__ bo, const int* __restrict__ dlen,
        float* __restrict__ pred, int t0, int Cc) {
    int b = blockIdx.y;
    int ct0 = blockIdx.x * 32;
    if (ct0 >= Cc) return;
    int steps_b = dlen[b];
    int l = threadIdx.x;
    int lhi = l >> 4, llo = l & 15;

    if (t0 + ct0 >= steps_b) {   // whole tile inactive: write -1
        for (int r = 0; r < 32; ++r) {
            int t = t0 + ct0 + r;
            if (r >= Cc - ct0 || t >= STEPS) break;
            float* pr = pred + ((size_t)b * STEPS + t) * VOCAB;
            for (int v = l; v < VOCAB; v += 64) pr[v] = -1.f;
        }
        return;
    }

    uint4 a[2][8];
    #pragma unroll
    for (int m = 0; m < 2; ++m) {
        int rr = ct0 + m * 16 + llo;
        int rc = (rr < Cc) ? rr : (Cc - 1);          // clamp (masked at store)
        const uint4* rp = (const uint4*)(hck + ((size_t)b * Cc + rc) * H);
        #pragma unroll
        for (int kt = 0; kt < 8; ++kt) a[m][kt] = rp[kt * 4 + lhi];
    }

    const uint4* bh4 = (const uint4*)woHi;
    const uint4* bl4 = (const uint4*)woLo;
    for (int vt = 0; vt < VT; ++vt) {
        int v = vt * 16 + llo;
        float bias = (v < VOCAB) ? bo[v] : 0.f;
        f32x4 acc0 = {bias, bias, bias, bias};
        f32x4 acc1 = acc0;
        #pragma unroll
        for (int kt = 0; kt < 8; ++kt) {
            uint4 bh = bh4[(vt * 8 + kt) * 64 + l];
            acc0 = mfma16(a[0][kt], bh, acc0);
            acc1 = mfma16(a[1][kt], bh, acc1);
        }
        #pragma unroll
        for (int kt = 0; kt < 8; ++kt) {
            uint4 bl = bl4[(vt * 8 + kt) * 64 + l];
            acc0 = mfma16(a[0][kt], bl, acc0);
            acc1 = mfma16(a[1][kt], bl, acc1);
        }
        if (v < VOCAB) {
            #pragma unroll
            for (int m = 0; m < 2; ++m) {
                f32x4 A = m ? acc1 : acc0;
                #pragma unroll
                for (int i = 0; i < 4; ++i) {
                    int r = ct0 + m * 16 + lhi * 4 + i;
                    int t = t0 + r;
                    if (r < Cc && t < STEPS)
                        pred[((size_t)b * STEPS + t) * VOCAB + v] =
                            (t < steps_b) ? A[i] : -1.f;
                }
            }
        }
    }
}

extern "C" void kernel_launch(void* const* d_in, const int* in_sizes, int n_in,
                              void* d_out, int out_size, void* d_ws, size_t ws_size,
                              hipStream_t stream) {
    const float* enc   = (const float*)d_in[0];
    const float* caps  = (const float*)d_in[1];
    const float* w_ih  = (const float*)d_in[2];
    const float* w_hh  = (const float*)d_in[3];
    const float* b_ih  = (const float*)d_in[4];
    const float* b_hh  = (const float*)d_in[5];
    const float* W_out = (const float*)d_in[6];
    const float* b_out = (const float*)d_in[7];
    const float* W_emb = (const float*)d_in[8];
    const float* b_emb = (const float*)d_in[9];
    const float* W_h   = (const float*)d_in[10];
    const float* b_h   = (const float*)d_in[11];
    const float* W_c   = (const float*)d_in[12];
    const float* b_c   = (const float*)d_in[13];
    const int*   lens  = (const int*)d_in[14];

    float* out_pred = (float*)d_out;
    float* out_caps = out_pred + (size_t)BS * STEPS * VOCAB;
    float* out_dec  = out_caps + (size_t)BS * T * WV;
    float* out_sidx = out_dec + BS;

    char* w = (char*)d_ws;
    size_t off = 0;
    auto take = [&](size_t bytes) -> char* {
        char* p = w + off;
        off += (bytes + 255) & ~(size_t)255;
        return p;
    };
    int*     sidx = (int*)take(BS * 4);
    int*     dlen = (int*)take(BS * 4);
    float*   Wc   = (float*)take((size_t)G4 * WV * 4);
    float*   bc   = (float*)take(G4 * 4);
    float*   h_st = (float*)take((size_t)BS * H * 4);
    float*   c_st = (float*)take((size_t)BS * H * 4);
    __half2* wR   = (__half2*)take((size_t)G4 * (H / 2) * 4);
    uint4*   woq  = (uint4*)take((size_t)8192 * 16);
    __half*  woHi = (__half*)take((size_t)VT * 8 * 64 * 8 * 2);
    __half*  woLo = (__half*)take((size_t)VT * 8 * 64 * 8 * 2);
    __half*  cHi  = (__half*)take((size_t)BS * T * 128 * 2);
    __half*  cLo  = (__half*)take((size_t)BS * T * 128 * 2);
    __half*  wcHi = (__half*)take((size_t)64 * 4 * 64 * 8 * 2);
    __half*  wcLo = (__half*)take((size_t)64 * 4 * 64 * 8 * 2);

    size_t rem = (ws_size > off) ? (ws_size - off) : 0;
    size_t per_step = (size_t)BS * G4 * 4 + (size_t)BS * H * 2 + 1024;
    int C = (int)(rem / per_step);
    if (C < 1) C = 1;
    if (C > STEPS) C = STEPS;
    float*  xg  = (float*)take((size_t)BS * C * G4 * 4);
    __half* hck = (__half*)take((size_t)BS * C * H * 2);

    (void)hipFuncSetAttribute((const void*)k_lstm,
                              hipFuncAttributeMaxDynamicSharedMemorySize, LSTM_SMEM);

    k_sort<<<1, 256, 0, stream>>>(lens, sidx, dlen, out_dec, out_sidx);
    k_gather<<<BS, 256, 0, stream>>>(caps, sidx, out_caps);
    k_wcomb<<<G4 * WV / 256, 256, 0, stream>>>(w_ih, W_emb, Wc);
    k_bcomb<<<G4 / 256, 256, 0, stream>>>(w_ih, b_ih, b_hh, b_emb, bc);
    k_packw<<<G4 * (H / 2) / 256, 256, 0, stream>>>(w_hh, wR);
    k_packo<<<8192 / 256, 256, 0, stream>>>(wR, woq);
    k_packwo<<<VT * 8 * 64 * 8 / 256, 256, 0, stream>>>(W_out, woHi, woLo);
    k_packcaps<<<BS * T * 128 / 256, 256, 0, stream>>>(out_caps, cHi, cLo);
    k_packwc<<<64 * 4 * 64 * 8 / 256, 256, 0, stream>>>(Wc, wcHi, wcLo);
    k_inithc<<<BS, 256, 0, stream>>>(enc, sidx, W_h, b_h, W_c, b_c, h_st, c_st);

    for (int t0 = 0; t0 < STEPS; t0 += C) {
        int Cc = STEPS - t0; if (Cc > C) Cc = C;
        dim3 gx((Cc + 31) / 32, BS);
        k_xg<<<gx, 256, 0, stream>>>(cHi, cLo, wcHi, wcLo, bc, dlen, xg, t0, Cc);
        k_lstm<<<BS, 512, LSTM_SMEM, stream>>>(wR, woq, xg, dlen, h_st, c_st, hck, t0, Cc);
        k_logits<<<gx, 64, 0, stream>>>(hck, woHi, woLo, b_out, dlen, out_pred, t0, Cc);
    }
}